// Round 10
// baseline (181.434 us; speedup 1.0000x reference)
//
#include <hip/hip_runtime.h>

// GAT fused v10 = v8 MINUS score-MFMA (bisect arm A).
// Keeps: double-buffered x tile, W fragments in regs, px 2-ahead prefetch,
// hardened non-draining barriers, alpha in regs.
// Scores: v7-proven f32 staging-pass dot products, now DOUBLE-BUFFERED
// (s_src2/s_dst2[2][64], slot = tile parity) since staging runs 1 tile ahead.

typedef __attribute__((ext_vector_type(8))) short short8;  // 8 bf16
typedef __attribute__((ext_vector_type(4))) float f32x4;

constexpr int   NTILES    = 8192;
constexpr int   GRID      = 768;      // 3 blocks/CU * 256 CUs
constexpr float NEG_SLOPE = 0.2f;
constexpr float LN_EPS    = 1e-5f;

__device__ __forceinline__ unsigned short f2bf(float f) {
    unsigned int u = __builtin_bit_cast(unsigned int, f);
    return (unsigned short)((u + 0x7FFFu + ((u >> 16) & 1u)) >> 16);
}
__device__ __forceinline__ unsigned pack2(float lo, float hi) {
    return (unsigned)f2bf(lo) | ((unsigned)f2bf(hi) << 16);
}
__device__ __forceinline__ unsigned swz256(int row, int bytecol) {
    return (unsigned)(row * 256 + bytecol) ^ (unsigned)((row & 7) << 4);
}
__device__ __forceinline__ unsigned swz128(int row, int bytecol) {
    return (unsigned)(row * 128 + bytecol) ^ (unsigned)((row & 7) << 4);
}

// Hardened non-draining barrier (no vmcnt drain; LDS fenced both ways).
#define LBAR() do {                                              \
    __builtin_amdgcn_sched_barrier(0);                           \
    asm volatile("s_waitcnt lgkmcnt(0)" ::: "memory");           \
    __builtin_amdgcn_s_barrier();                                \
    __builtin_amdgcn_sched_barrier(0);                           \
} while (0)

// Stage x tile (from px regs) into buf (bf16, swz256) AND compute f32 scores
// into psrc/pdst (one slot of the double-buffered score arrays).
#define STAGE_AND_SCORES(buf, psrc, pdst)                                     \
    do {                                                                      \
        _Pragma("unroll")                                                     \
        for (int c = 0; c < 4; ++c) {                                         \
            const float4 v0 = px[2*c], v1 = px[2*c+1];                        \
            float ps = v0.x*wsr[0] + v0.y*wsr[1] + v0.z*wsr[2] + v0.w*wsr[3]  \
                     + v1.x*wsr[4] + v1.y*wsr[5] + v1.z*wsr[6] + v1.w*wsr[7]; \
            float pd = v0.x*wdr[0] + v0.y*wdr[1] + v0.z*wdr[2] + v0.w*wdr[3]  \
                     + v1.x*wdr[4] + v1.y*wdr[5] + v1.z*wdr[6] + v1.w*wdr[7]; \
            uint4 pk;                                                         \
            pk.x = pack2(v0.x, v0.y); pk.y = pack2(v0.z, v0.w);               \
            pk.z = pack2(v1.x, v1.y); pk.w = pack2(v1.z, v1.w);               \
            const int m = (t >> 4) + 16 * c;                                  \
            *(uint4*)((char*)(buf) + swz256(m, (t & 15) * 16)) = pk;          \
            _Pragma("unroll")                                                 \
            for (int msk = 1; msk < 16; msk <<= 1) {                          \
                ps += __shfl_xor(ps, msk, 64);                                \
                pd += __shfl_xor(pd, msk, 64);                                \
            }                                                                 \
            if ((t & 15) == 0) { (psrc)[m] = ps; (pdst)[m] = pd; }            \
        }                                                                     \
    } while (0)

__launch_bounds__(256, 3)
__global__ void gat_mfma10(const float* __restrict__ x,
                           const float* __restrict__ W,
                           const float* __restrict__ a_src,
                           const float* __restrict__ a_dst,
                           const float* __restrict__ gamma,
                           const float* __restrict__ beta,
                           float* __restrict__ out)
{
    __shared__ __align__(16) unsigned short sB0[64 * 128]; // x (swz256) / h^T (swz128)
    __shared__ __align__(16) unsigned short sB1[64 * 128]; // double buffer
    __shared__ __align__(16) float s_src2[2][64];
    __shared__ __align__(16) float s_dst2[2][64];
    __shared__ __align__(16) float s_ws[128];
    __shared__ __align__(16) float s_wd[128];
    __shared__ __align__(16) float s_g[128];
    __shared__ __align__(16) float s_b[128];

    const int t    = threadIdx.x;
    const int lane = t & 63;
    const int w    = t >> 6;      // wave 0..3
    const int l15  = lane & 15;
    const int lg   = lane >> 4;   // 0..3

    // ---- one-time: ws = W@a_src, wd = W@a_dst ; gamma/beta ----
    if (t < 128) {
        const float4* W4  = reinterpret_cast<const float4*>(W) + t * 32;
        const float4* as4 = reinterpret_cast<const float4*>(a_src);
        const float4* ad4 = reinterpret_cast<const float4*>(a_dst);
        float ws = 0.f, wd = 0.f;
        for (int n4 = 0; n4 < 32; ++n4) {
            float4 wr = W4[n4], as = as4[n4], ad = ad4[n4];
            ws += wr.x*as.x + wr.y*as.y + wr.z*as.z + wr.w*as.w;
            wd += wr.x*ad.x + wr.y*ad.y + wr.z*ad.z + wr.w*ad.w;
        }
        s_ws[t] = ws; s_wd[t] = wd;
        s_g[t] = gamma[t]; s_b[t] = beta[t];
    }

    // ---- one-time: W B-fragments -> registers (v4-proven layout) ----
    short8 wfrag[2][4];   // [nb][kb]; lane holds W[k=kb*32+lg*8+q][n=32w+nb*16+l15]
    #pragma unroll
    for (int nb = 0; nb < 2; ++nb) {
        #pragma unroll
        for (int kb = 0; kb < 4; ++kb) {
            const int n = 32 * w + nb * 16 + l15;
            float v[8];
            #pragma unroll
            for (int q = 0; q < 8; ++q)
                v[q] = W[(kb * 32 + lg * 8 + q) * 128 + n];
            uint4 pfr;
            pfr.x = pack2(v[0], v[1]); pfr.y = pack2(v[2], v[3]);
            pfr.z = pack2(v[4], v[5]); pfr.w = pack2(v[6], v[7]);
            wfrag[nb][kb] = __builtin_bit_cast(short8, pfr);
        }
    }
    __syncthreads();   // s_ws/s_wd visible

    // per-thread ws/wd slices for staging-pass score partials
    float wsr[8], wdr[8];
    {
        const int k0 = (t & 15) * 8;
        #pragma unroll
        for (int q = 0; q < 8; ++q) { wsr[q] = s_ws[k0 + q]; wdr[q] = s_wd[k0 + q]; }
    }

    // ---- prologue: stage tile 0 (+scores slot 0); prefetch tile GRID ----
    float4 px[8];
    {
        const float4* x4 = reinterpret_cast<const float4*>(x + (size_t)blockIdx.x * 8192);
        #pragma unroll
        for (int c = 0; c < 4; ++c) {
            const int idx8 = t + 256 * c;
            px[2*c]   = x4[idx8 * 2];
            px[2*c+1] = x4[idx8 * 2 + 1];
        }
    }
    STAGE_AND_SCORES(sB0, s_src2[0], s_dst2[0]);
    {
        const float4* xn = reinterpret_cast<const float4*>(x + (size_t)(blockIdx.x + GRID) * 8192);
        #pragma unroll
        for (int c = 0; c < 4; ++c) {
            const int idx8 = t + 256 * c;
            px[2*c]   = xn[idx8 * 2];
            px[2*c+1] = xn[idx8 * 2 + 1];
        }
    }
    __syncthreads();   // sB0 + scores[0] staged

    int p = 0;
    for (int tile = blockIdx.x; tile < NTILES; tile += GRID) {
        float* ob = out + (size_t)tile * 8192;
        unsigned short* cur = p ? sB1 : sB0;
        unsigned short* nxt = p ? sB0 : sB1;

        // ---- region 1: stage x_{n+1}+scores[p^1] -> nxt ; refill px ; GEMM1 on cur ----
        if (tile + GRID < NTILES) {
            STAGE_AND_SCORES(nxt, s_src2[p ^ 1], s_dst2[p ^ 1]);
        }
        if (tile + 2 * GRID < NTILES) {
            const float4* xn = reinterpret_cast<const float4*>(x + (size_t)(tile + 2 * GRID) * 8192);
            #pragma unroll
            for (int c = 0; c < 4; ++c) {
                const int idx8 = t + 256 * c;
                px[2*c]   = xn[idx8 * 2];
                px[2*c+1] = xn[idx8 * 2 + 1];
            }
        }

        f32x4 acc[4][2];
        #pragma unroll
        for (int mi = 0; mi < 4; ++mi) {
            acc[mi][0] = f32x4{0.f,0.f,0.f,0.f};
            acc[mi][1] = f32x4{0.f,0.f,0.f,0.f};
        }
        #pragma unroll
        for (int kb = 0; kb < 4; ++kb) {
            const int kbyte = kb * 64 + lg * 16;
            #pragma unroll
            for (int mi = 0; mi < 4; ++mi) {
                short8 afr = *(const short8*)((char*)cur + swz256(mi * 16 + l15, kbyte));
                acc[mi][0] = __builtin_amdgcn_mfma_f32_16x16x32_bf16(afr, wfrag[0][kb], acc[mi][0], 0, 0, 0);
                acc[mi][1] = __builtin_amdgcn_mfma_f32_16x16x32_bf16(afr, wfrag[1][kb], acc[mi][1], 0, 0, 0);
            }
        }
        LBAR();   // S2: GEMM1 reads of cur + staging writes of nxt complete

        // ---- region 3: h^T (swz128) over cur ----
        #pragma unroll
        for (int mi = 0; mi < 4; ++mi) {
            const int m0 = mi * 16 + lg * 4;
            #pragma unroll
            for (int nb = 0; nb < 2; ++nb) {
                const int n = 32 * w + nb * 16 + l15;
                uint2 pk;
                pk.x = pack2(acc[mi][nb][0], acc[mi][nb][1]);
                pk.y = pack2(acc[mi][nb][2], acc[mi][nb][3]);
                *(uint2*)((char*)cur + swz128(n, m0 * 2)) = pk;
            }
        }
        LBAR();   // S3: h^T visible

        // ---- region 5: softmax (scores slot p) -> alpha regs ; GEMM2 ; LN ; store ----
        short8 pa0, pa1;
        {
            const float* s_src = s_src2[p];
            const float* s_dst = s_dst2[p];
            const float srci = s_src[w * 16 + l15];
            const float4 dA0 = *(const float4*)&s_dst[lg * 8];
            const float4 dA1 = *(const float4*)&s_dst[lg * 8 + 4];
            const float4 dB0 = *(const float4*)&s_dst[32 + lg * 8];
            const float4 dB1 = *(const float4*)&s_dst[32 + lg * 8 + 4];
            float e[16] = { srci+dA0.x, srci+dA0.y, srci+dA0.z, srci+dA0.w,
                            srci+dA1.x, srci+dA1.y, srci+dA1.z, srci+dA1.w,
                            srci+dB0.x, srci+dB0.y, srci+dB0.z, srci+dB0.w,
                            srci+dB1.x, srci+dB1.y, srci+dB1.z, srci+dB1.w };
            float mx = -1e30f;
            #pragma unroll
            for (int q = 0; q < 16; ++q) {
                e[q] = (e[q] >= 0.f) ? e[q] : NEG_SLOPE * e[q];
                mx = fmaxf(mx, e[q]);
            }
            mx = fmaxf(mx, __shfl_xor(mx, 16, 64));
            mx = fmaxf(mx, __shfl_xor(mx, 32, 64));
            float sm = 0.f;
            #pragma unroll
            for (int q = 0; q < 16; ++q) { e[q] = __expf(e[q] - mx); sm += e[q]; }
            sm += __shfl_xor(sm, 16, 64);
            sm += __shfl_xor(sm, 32, 64);
            const float inv = 1.0f / sm;
            uint4 p0, p1;
            p0.x = pack2(e[0]*inv,  e[1]*inv);  p0.y = pack2(e[2]*inv,  e[3]*inv);
            p0.z = pack2(e[4]*inv,  e[5]*inv);  p0.w = pack2(e[6]*inv,  e[7]*inv);
            p1.x = pack2(e[8]*inv,  e[9]*inv);  p1.y = pack2(e[10]*inv, e[11]*inv);
            p1.z = pack2(e[12]*inv, e[13]*inv); p1.w = pack2(e[14]*inv, e[15]*inv);
            pa0 = __builtin_bit_cast(short8, p0);
            pa1 = __builtin_bit_cast(short8, p1);
        }

        f32x4 o[8];
        #pragma unroll
        for (int mi = 0; mi < 8; ++mi) o[mi] = f32x4{0.f,0.f,0.f,0.f};
        #pragma unroll
        for (int kb = 0; kb < 2; ++kb) {
            const int jbyte = kb * 64 + lg * 16;
            const short8 bfr = (kb == 0) ? pa0 : pa1;
            #pragma unroll
            for (int mi = 0; mi < 8; ++mi) {
                short8 afr = *(const short8*)((char*)cur + swz128(mi * 16 + l15, jbyte));
                o[mi] = __builtin_amdgcn_mfma_f32_16x16x32_bf16(afr, bfr, o[mi], 0, 0, 0);
            }
        }

        float sm1 = 0.f, sm2 = 0.f;
        #pragma unroll
        for (int mi = 0; mi < 8; ++mi) {
            #pragma unroll
            for (int r = 0; r < 4; ++r) { const float v = o[mi][r]; sm1 += v; sm2 += v * v; }
        }
        sm1 += __shfl_xor(sm1, 16, 64); sm2 += __shfl_xor(sm2, 16, 64);
        sm1 += __shfl_xor(sm1, 32, 64); sm2 += __shfl_xor(sm2, 32, 64);
        const float mu   = sm1 * (1.f / 128.f);
        const float var  = sm2 * (1.f / 128.f) - mu * mu;
        const float rstd = rsqrtf(var + LN_EPS);

        float* orow = ob + (w * 16 + l15) * 128;
        #pragma unroll
        for (int mi = 0; mi < 8; ++mi) {
            const int n0 = mi * 16 + lg * 4;
            const float4 gv = *(const float4*)&s_g[n0];
            const float4 bv = *(const float4*)&s_b[n0];
            float4 vo;
            vo.x = fmaxf((o[mi][0] - mu) * rstd * gv.x + bv.x, 0.f);
            vo.y = fmaxf((o[mi][1] - mu) * rstd * gv.y + bv.y, 0.f);
            vo.z = fmaxf((o[mi][2] - mu) * rstd * gv.z + bv.z, 0.f);
            vo.w = fmaxf((o[mi][3] - mu) * rstd * gv.w + bv.w, 0.f);
            *(float4*)(orow + n0) = vo;
        }
        LBAR();   // S_loop: GEMM2 reads of cur done before next iter restages it
        p ^= 1;
    }
}

extern "C" void kernel_launch(void* const* d_in, const int* in_sizes, int n_in,
                              void* d_out, int out_size, void* d_ws, size_t ws_size,
                              hipStream_t stream) {
    const float* x   = (const float*)d_in[0];
    const float* W   = (const float*)d_in[1];
    const float* asv = (const float*)d_in[2];
    const float* adv = (const float*)d_in[3];
    const float* gm  = (const float*)d_in[4];
    const float* bt  = (const float*)d_in[5];
    float* out = (float*)d_out;

    hipLaunchKernelGGL(gat_mfma10, dim3(GRID), dim3(256), 0, stream,
                       x, W, asv, adv, gm, bt, out);
}